// Round 8
// baseline (201.814 us; speedup 1.0000x reference)
//
#include <hip/hip_runtime.h>

// Decoder: h = relu(x @ W1 + b1); out = clamp(0.25*(h @ W2 + b2) + 0.5, 0, 1)
// B=262144, F=16, H=24, NOUT=784. Memory-bound: 822 MB fp32 output write.
//
// History:
//  R1/R3/R4: fp32 96-VGPR W2 array spills under any launch_bounds cap.
//  R2: (256,2), fp32 fma -> 208 us.
//  R6: f16 packed v_dot2_f32_f16 at (256,3) -> 182.5 us (4.6 TB/s; the
//      fill kernel proves 6.7-6.85 TB/s store path on this chip).
//  R7: __builtin_nontemporal_* rejects HIP_vector_type (struct) -> compile
//      fail. Fix: use clang ext_vector float4 for NT accesses.
//  This round (= R6 theory): (a) software-pipeline hbuf reads (prefetch row
//      r+1 during row r's dot2 chain), (b) NT stores for out + NT loads for
//      x (write/read-once; keep W2 resident in L2).

typedef _Float16 h2_t __attribute__((ext_vector_type(2)));
typedef float    f4_t __attribute__((ext_vector_type(4)));

static __device__ __forceinline__ unsigned int pk_h2(float lo, float hi) {
    return __builtin_bit_cast(unsigned int, __builtin_amdgcn_cvt_pkrtz(lo, hi));
}

#if __has_builtin(__builtin_amdgcn_fdot2)
static __device__ __forceinline__ float fdot2u(unsigned int a, unsigned int b, float c) {
    return __builtin_amdgcn_fdot2(__builtin_bit_cast(h2_t, a),
                                  __builtin_bit_cast(h2_t, b), c, false);
}
#else
static __device__ __forceinline__ float fdot2u(unsigned int a, unsigned int b, float c) {
    const h2_t av = __builtin_bit_cast(h2_t, a);
    const h2_t bv = __builtin_bit_cast(h2_t, b);
    return fmaf((float)av.y, (float)bv.y, fmaf((float)av.x, (float)bv.x, c));
}
#endif

#define THREADS 256
#define ROWS_PER_BLOCK 256
#define F 16
#define H 24
#define KP 12               // half2 pairs along the K=24 reduction
#define NOUT 784
#define NCHUNK (NOUT / 4)   // 196 float4 column-chunks per row

__launch_bounds__(THREADS, 3)
__global__ void decoder_kernel(const float* __restrict__ x,
                               const float* __restrict__ W1,
                               const float* __restrict__ b1,
                               const float* __restrict__ W2,
                               const float* __restrict__ b2,
                               float* __restrict__ out) {
    __shared__ float w1t[H][F];                       // W1^T
    __shared__ float b1s[H];
    __shared__ unsigned int hbuf[ROWS_PER_BLOCK][KP]; // h packed half2, 12 KB

    const int tid  = threadIdx.x;
    const int row0 = blockIdx.x * ROWS_PER_BLOCK;

    // ---- stage W1^T and b1 into LDS
    for (int idx = tid; idx < F * H; idx += THREADS) {
        const int i = idx / H, j = idx % H;           // W1 is [F][H] row-major
        w1t[j][i] = W1[idx];
    }
    if (tid < H) b1s[tid] = b1[tid];

    // ---- load this thread's x row (16 floats = 4 x f4), NT (read-once)
    f4_t xv[4];
    {
        const f4_t* xr = reinterpret_cast<const f4_t*>(x + (size_t)(row0 + tid) * F);
        #pragma unroll
        for (int q = 0; q < 4; ++q)
            xv[q] = __builtin_nontemporal_load(&xr[q]);
    }

    __syncthreads();

    // ---- phase 1: h = relu(x @ W1 + b1); pack pairs to half2
    #pragma unroll
    for (int g = 0; g < 3; ++g) {
        float hj[8];
        #pragma unroll
        for (int jj = 0; jj < 8; ++jj) {
            const int j = g * 8 + jj;
            float acc = b1s[j];
            #pragma unroll
            for (int q = 0; q < 4; ++q) {
                const f4_t wv = *reinterpret_cast<const f4_t*>(&w1t[j][q * 4]);
                acc = fmaf(xv[q].x, wv.x, acc);
                acc = fmaf(xv[q].y, wv.y, acc);
                acc = fmaf(xv[q].z, wv.z, acc);
                acc = fmaf(xv[q].w, wv.w, acc);
            }
            hj[jj] = fmaxf(acc, 0.0f);
        }
        uint4 p;
        p.x = pk_h2(hj[0], hj[1]);
        p.y = pk_h2(hj[2], hj[3]);
        p.z = pk_h2(hj[4], hj[5]);
        p.w = pk_h2(hj[6], hj[7]);
        *reinterpret_cast<uint4*>(&hbuf[tid][g * 4]) = p;
    }

    __syncthreads();

    // ---- phase 2: thread owns output cols [c0, c0+3] for all 256 rows.
    // W2 packed half2 (pre-scaled 0.25) in 48 u32 regs; bias folded.
    const int cc = (tid < NCHUNK) ? tid : (NCHUNK - 1);  // clamp, no branch
    const int c0 = cc * 4;

    unsigned int w2p[KP][4];
    #pragma unroll
    for (int kp = 0; kp < KP; ++kp) {
        const float4 a = *reinterpret_cast<const float4*>(&W2[(2 * kp + 0) * NOUT + c0]);
        const float4 b = *reinterpret_cast<const float4*>(&W2[(2 * kp + 1) * NOUT + c0]);
        w2p[kp][0] = pk_h2(0.25f * a.x, 0.25f * b.x);
        w2p[kp][1] = pk_h2(0.25f * a.y, 0.25f * b.y);
        w2p[kp][2] = pk_h2(0.25f * a.z, 0.25f * b.z);
        w2p[kp][3] = pk_h2(0.25f * a.w, 0.25f * b.w);
    }
    float4 b2v = *reinterpret_cast<const float4*>(&b2[c0]);
    b2v.x = fmaf(b2v.x, 0.25f, 0.5f);
    b2v.y = fmaf(b2v.y, 0.25f, 0.5f);
    b2v.z = fmaf(b2v.z, 0.25f, 0.5f);
    b2v.w = fmaf(b2v.w, 0.25f, 0.5f);

    if (tid < NCHUNK) {
        float* outp = out + (size_t)row0 * NOUT + c0;

        // software pipeline: hold row r's h in regs, prefetch row r+1
        uint4 hc0 = *reinterpret_cast<const uint4*>(&hbuf[0][0]);
        uint4 hc1 = *reinterpret_cast<const uint4*>(&hbuf[0][4]);
        uint4 hc2 = *reinterpret_cast<const uint4*>(&hbuf[0][8]);

        for (int r = 0; r < ROWS_PER_BLOCK; ++r) {
            const int rn = (r + 1) & (ROWS_PER_BLOCK - 1);   // wraps; row 0 reread
            const uint4 n0 = *reinterpret_cast<const uint4*>(&hbuf[rn][0]);
            const uint4 n1 = *reinterpret_cast<const uint4*>(&hbuf[rn][4]);
            const uint4 n2 = *reinterpret_cast<const uint4*>(&hbuf[rn][8]);

            float4 acc = b2v;
#define DOT_STEP(hword, kp)                         \
            acc.x = fdot2u((hword), w2p[kp][0], acc.x); \
            acc.y = fdot2u((hword), w2p[kp][1], acc.y); \
            acc.z = fdot2u((hword), w2p[kp][2], acc.z); \
            acc.w = fdot2u((hword), w2p[kp][3], acc.w);
            DOT_STEP(hc0.x, 0)  DOT_STEP(hc0.y, 1)
            DOT_STEP(hc0.z, 2)  DOT_STEP(hc0.w, 3)
            DOT_STEP(hc1.x, 4)  DOT_STEP(hc1.y, 5)
            DOT_STEP(hc1.z, 6)  DOT_STEP(hc1.w, 7)
            DOT_STEP(hc2.x, 8)  DOT_STEP(hc2.y, 9)
            DOT_STEP(hc2.z, 10) DOT_STEP(hc2.w, 11)
#undef DOT_STEP

            f4_t o;
            o.x = fminf(fmaxf(acc.x, 0.f), 1.f);
            o.y = fminf(fmaxf(acc.y, 0.f), 1.f);
            o.z = fminf(fmaxf(acc.z, 0.f), 1.f);
            o.w = fminf(fmaxf(acc.w, 0.f), 1.f);
            __builtin_nontemporal_store(o, reinterpret_cast<f4_t*>(outp));
            outp += NOUT;

            hc0 = n0; hc1 = n1; hc2 = n2;
        }
    }
}

extern "C" void kernel_launch(void* const* d_in, const int* in_sizes, int n_in,
                              void* d_out, int out_size, void* d_ws, size_t ws_size,
                              hipStream_t stream) {
    const float* x  = (const float*)d_in[0];
    const float* W1 = (const float*)d_in[1];
    const float* b1 = (const float*)d_in[2];
    const float* W2 = (const float*)d_in[3];
    const float* b2 = (const float*)d_in[4];
    float* out = (float*)d_out;

    const int B = in_sizes[0] / F;              // 262144
    const int grid = B / ROWS_PER_BLOCK;        // 1024
    decoder_kernel<<<grid, THREADS, 0, stream>>>(x, W1, b1, W2, b2, out);
}

// Round 9
// 183.891 us; speedup vs baseline: 1.0975x; 1.0975x over previous
//
#include <hip/hip_runtime.h>

// Decoder: h = relu(x @ W1 + b1); out = clamp(0.25*(h @ W2 + b2) + 0.5, 0, 1)
// B=262144, F=16, H=24, NOUT=784. Memory-bound: 822 MB fp32 output write.
//
// History:
//  R1/R3/R4: fp32 96-VGPR W2 array spills under any launch_bounds cap.
//  R2: (256,2), fp32 fma -> 208 us.
//  R6: f16 packed v_dot2_f32_f16, (256,3) -> 182.5 us (4.6 TB/s vs 6.85
//      proven store path). BEST so far.
//  R8: R6 + sw-pipeline + NT stores -> 201.8 us REGRESSION (extra live regs /
//      NT bypasses L2 write path). Reverted both.
//  This round: exact R6 + ONE change: launch_bounds (256,3)->(256,4).
//      f16 regs (~80 live) now fit the 128 cap; 4 waves/SIMD (+33% store
//      concurrency) attacks the 182-vs-130us store-BW gap.

typedef _Float16 h2_t __attribute__((ext_vector_type(2)));

static __device__ __forceinline__ unsigned int pk_h2(float lo, float hi) {
    return __builtin_bit_cast(unsigned int, __builtin_amdgcn_cvt_pkrtz(lo, hi));
}

#if __has_builtin(__builtin_amdgcn_fdot2)
static __device__ __forceinline__ float fdot2u(unsigned int a, unsigned int b, float c) {
    return __builtin_amdgcn_fdot2(__builtin_bit_cast(h2_t, a),
                                  __builtin_bit_cast(h2_t, b), c, false);
}
#else
static __device__ __forceinline__ float fdot2u(unsigned int a, unsigned int b, float c) {
    const h2_t av = __builtin_bit_cast(h2_t, a);
    const h2_t bv = __builtin_bit_cast(h2_t, b);
    return fmaf((float)av.y, (float)bv.y, fmaf((float)av.x, (float)bv.x, c));
}
#endif

#define THREADS 256
#define ROWS_PER_BLOCK 256
#define F 16
#define H 24
#define KP 12               // half2 pairs along the K=24 reduction
#define NOUT 784
#define NCHUNK (NOUT / 4)   // 196 float4 column-chunks per row

__launch_bounds__(THREADS, 4)
__global__ void decoder_kernel(const float* __restrict__ x,
                               const float* __restrict__ W1,
                               const float* __restrict__ b1,
                               const float* __restrict__ W2,
                               const float* __restrict__ b2,
                               float* __restrict__ out) {
    __shared__ float w1t[H][F];                       // W1^T
    __shared__ float b1s[H];
    __shared__ unsigned int hbuf[ROWS_PER_BLOCK][KP]; // h packed half2, 12 KB

    const int tid  = threadIdx.x;
    const int row0 = blockIdx.x * ROWS_PER_BLOCK;

    // ---- stage W1^T and b1 into LDS
    for (int idx = tid; idx < F * H; idx += THREADS) {
        const int i = idx / H, j = idx % H;           // W1 is [F][H] row-major
        w1t[j][i] = W1[idx];
    }
    if (tid < H) b1s[tid] = b1[tid];

    // ---- load this thread's x row (16 floats = 4 x float4)
    float4 xv[4];
    {
        const float* xr = x + (size_t)(row0 + tid) * F;
        #pragma unroll
        for (int q = 0; q < 4; ++q)
            xv[q] = *reinterpret_cast<const float4*>(&xr[q * 4]);
    }

    __syncthreads();

    // ---- phase 1: h = relu(x @ W1 + b1); pack pairs to half2
    #pragma unroll
    for (int g = 0; g < 3; ++g) {
        float hj[8];
        #pragma unroll
        for (int jj = 0; jj < 8; ++jj) {
            const int j = g * 8 + jj;
            float acc = b1s[j];
            #pragma unroll
            for (int q = 0; q < 4; ++q) {
                const float4 wv = *reinterpret_cast<const float4*>(&w1t[j][q * 4]);
                acc = fmaf(xv[q].x, wv.x, acc);
                acc = fmaf(xv[q].y, wv.y, acc);
                acc = fmaf(xv[q].z, wv.z, acc);
                acc = fmaf(xv[q].w, wv.w, acc);
            }
            hj[jj] = fmaxf(acc, 0.0f);
        }
        uint4 p;
        p.x = pk_h2(hj[0], hj[1]);
        p.y = pk_h2(hj[2], hj[3]);
        p.z = pk_h2(hj[4], hj[5]);
        p.w = pk_h2(hj[6], hj[7]);
        *reinterpret_cast<uint4*>(&hbuf[tid][g * 4]) = p;
    }

    __syncthreads();

    // ---- phase 2: thread owns output cols [c0, c0+3] for all 256 rows.
    // W2 packed half2 (pre-scaled 0.25) in 48 u32 regs; bias folded.
    const int cc = (tid < NCHUNK) ? tid : (NCHUNK - 1);  // clamp, no branch
    const int c0 = cc * 4;

    unsigned int w2p[KP][4];
    #pragma unroll
    for (int kp = 0; kp < KP; ++kp) {
        const float4 a = *reinterpret_cast<const float4*>(&W2[(2 * kp + 0) * NOUT + c0]);
        const float4 b = *reinterpret_cast<const float4*>(&W2[(2 * kp + 1) * NOUT + c0]);
        w2p[kp][0] = pk_h2(0.25f * a.x, 0.25f * b.x);
        w2p[kp][1] = pk_h2(0.25f * a.y, 0.25f * b.y);
        w2p[kp][2] = pk_h2(0.25f * a.z, 0.25f * b.z);
        w2p[kp][3] = pk_h2(0.25f * a.w, 0.25f * b.w);
    }
    float4 b2v = *reinterpret_cast<const float4*>(&b2[c0]);
    b2v.x = fmaf(b2v.x, 0.25f, 0.5f);
    b2v.y = fmaf(b2v.y, 0.25f, 0.5f);
    b2v.z = fmaf(b2v.z, 0.25f, 0.5f);
    b2v.w = fmaf(b2v.w, 0.25f, 0.5f);

    if (tid < NCHUNK) {
        float* outp = out + (size_t)row0 * NOUT + c0;
        for (int r = 0; r < ROWS_PER_BLOCK; ++r) {
            // h row: 3 uniform-address (broadcast) b128 reads = 12 half2
            const uint4 h0 = *reinterpret_cast<const uint4*>(&hbuf[r][0]);
            const uint4 h1 = *reinterpret_cast<const uint4*>(&hbuf[r][4]);
            const uint4 h2 = *reinterpret_cast<const uint4*>(&hbuf[r][8]);
            unsigned int hw[KP];
            hw[0] = h0.x; hw[1]  = h0.y; hw[2]  = h0.z; hw[3]  = h0.w;
            hw[4] = h1.x; hw[5]  = h1.y; hw[6]  = h1.z; hw[7]  = h1.w;
            hw[8] = h2.x; hw[9]  = h2.y; hw[10] = h2.z; hw[11] = h2.w;

            float4 acc = b2v;
            #pragma unroll
            for (int kp = 0; kp < KP; ++kp) {
                acc.x = fdot2u(hw[kp], w2p[kp][0], acc.x);
                acc.y = fdot2u(hw[kp], w2p[kp][1], acc.y);
                acc.z = fdot2u(hw[kp], w2p[kp][2], acc.z);
                acc.w = fdot2u(hw[kp], w2p[kp][3], acc.w);
            }
            float4 o;
            o.x = fminf(fmaxf(acc.x, 0.f), 1.f);
            o.y = fminf(fmaxf(acc.y, 0.f), 1.f);
            o.z = fminf(fmaxf(acc.z, 0.f), 1.f);
            o.w = fminf(fmaxf(acc.w, 0.f), 1.f);
            *reinterpret_cast<float4*>(outp) = o;
            outp += NOUT;
        }
    }
}

extern "C" void kernel_launch(void* const* d_in, const int* in_sizes, int n_in,
                              void* d_out, int out_size, void* d_ws, size_t ws_size,
                              hipStream_t stream) {
    const float* x  = (const float*)d_in[0];
    const float* W1 = (const float*)d_in[1];
    const float* b1 = (const float*)d_in[2];
    const float* W2 = (const float*)d_in[3];
    const float* b2 = (const float*)d_in[4];
    float* out = (float*)d_out;

    const int B = in_sizes[0] / F;              // 262144
    const int grid = B / ROWS_PER_BLOCK;        // 1024
    decoder_kernel<<<grid, THREADS, 0, stream>>>(x, W1, b1, W2, b2, out);
}